// Round 22
// baseline (124.085 us; speedup 1.0000x reference)
//
#include <hip/hip_runtime.h>
#include <stdint.h>

#define M_TOK 512
#define N_OUT 11008
#define K_IN  4096
#define BM 512
#define BN 64
#define BKS 256                 // k per barrier span (4 MFMA k-tiles)
#define NSPAN (K_IN / BKS)      // 16

typedef int i32x4 __attribute__((ext_vector_type(4)));

// =============================================================================
// Pre-pass: per-token-row int8 quantization of x (absmax/127), emitted in
// MFMA-FRAGMENT layout: chunk (kc16 = k>>4, gm = m>>4) stored at
//   x8f[((kc16*32) + gm)*256 + (m&15)*16 + (k&15)]
// A-frag load = fully coalesced dwordx4 from the L2-resident 2MB buffer.
// Verified rounds 11-21 (absmax 4.125).
// =============================================================================
__global__ void xquant_kernel(const float* __restrict__ x, int8_t* __restrict__ x8f,
                              float* __restrict__ sx) {
  const int row = blockIdx.x * 4 + (threadIdx.x >> 6);
  const int lane = threadIdx.x & 63;
  const float4* xr = (const float4*)(x + (size_t)row * K_IN);

  float4 v[16];
  float m = 0.f;
#pragma unroll
  for (int j = 0; j < 16; ++j) {
    v[j] = xr[lane * 16 + j];
    m = fmaxf(m, fmaxf(fmaxf(fabsf(v[j].x), fabsf(v[j].y)),
                       fmaxf(fabsf(v[j].z), fabsf(v[j].w))));
  }
#pragma unroll
  for (int o = 32; o; o >>= 1) m = fmaxf(m, __shfl_xor(m, o));

  const float inv = 127.0f / m;
  if (lane == 0) sx[row] = m / 127.0f;

  uint32_t d[16];
#pragma unroll
  for (int j = 0; j < 16; ++j) {
    int a = __float2int_rn(v[j].x * inv);
    int b = __float2int_rn(v[j].y * inv);
    int c = __float2int_rn(v[j].z * inv);
    int e = __float2int_rn(v[j].w * inv);
    d[j] = (a & 0xFF) | ((b & 0xFF) << 8) | ((c & 0xFF) << 16) | (e << 24);
  }
  const int gm = row >> 4, mr = row & 15;
#pragma unroll
  for (int q = 0; q < 4; ++q) {
    const int kc16 = lane * 4 + q;
    *(uint4*)&x8f[(size_t)(kc16 * 32 + gm) * 256 + mr * 16] =
        make_uint4(d[4 * q], d[4 * q + 1], d[4 * q + 2], d[4 * q + 3]);
  }
}

// =============================================================================
// int8 GEMM, BM=512 (all of M) x BN=64, NO K-split, grid 172 x 1024 thr.
// r20 base (best: 60.9us) + ONE change: A prefetch for span t+1 is WOVEN INTO
// COMPUTE (aC/aN double-buffer, x2-unrolled -> all-static names, rule #20).
// Per kk-group: 4x ds_read_b128 (b frags) -> issue 2 A-frag global loads for
// the NEXT span -> 8 MFMA. The A TA burst (~2k cyc) now overlaps COMPUTE's
// LDS phase instead of following it (r20 serialized them: 8.1k cyc/span
// measured vs 3.1k TA + 3.1k LDS).
//   - B: write-at-top (full-span load cover), issue t+2 at top. Unchanged.
//   - lgkm-only raw barriers; global loads fly across (counted waits at use).
//   - LDS [64 rows][256 int8], ch = c ^ (row&15): 2-way alias = free.
// =============================================================================
__global__ __launch_bounds__(1024, 4)
void qgemm_i8(const int8_t* __restrict__ x8f, const float* __restrict__ sx,
              const int* __restrict__ qw, const float* __restrict__ scale,
              const float* __restrict__ bias, float* __restrict__ out) {
  __shared__ __align__(16) int8_t Bs[2][BN * BKS];  // 16KB each (32KB total)

  const int tid = threadIdx.x;
  const int lane = tid & 63;
  const int wm = tid >> 6;  // 0..15: wave owns rows wm*32 .. wm*32+31
  const int kc = lane >> 4;

  const int bn0 = blockIdx.x * BN;
  const int gmbase = wm * 2;  // gm = m>>4

  i32x4 acc[2][4] = {};
  i32x4 aC[8], aN[8];  // A frags: current span / next span (static names)
  int4 br[4];          // 64B of one W row; write-at-top -> full-span cover

  const int brow = tid >> 4;  // 0..63: W row within the BN tile
  const int bq = tid & 15;    // 64B unit within the 1024B int32 row span

#define LGKM_BAR() asm volatile("s_waitcnt lgkmcnt(0)\ns_barrier" ::: "memory")

  // bulk A load (prologue only)
#define A_ISSUE_ALL(k0, DST)                                                     \
  {                                                                              \
    const int kbase16 = (k0) >> 4;                                               \
    _Pragma("unroll") for (int kk = 0; kk < 4; ++kk) {                           \
      _Pragma("unroll") for (int mi = 0; mi < 2; ++mi) {                         \
        DST[kk * 2 + mi] =                                                       \
            *(const i32x4*)&x8f[(size_t)((kbase16 + kk * 4 + kc) * 32 + gmbase + mi) * 256 + \
                                (lane & 15) * 16];                               \
      }                                                                          \
    }                                                                            \
  }

#define B_ISSUE(k0)                                                              \
  {                                                                              \
    const int4* bp = (const int4*)(qw + (size_t)(bn0 + brow) * K_IN + (k0) + bq * 16); \
    _Pragma("unroll") for (int k = 0; k < 4; ++k) br[k] = bp[k];                 \
  }

#define B_WRITE(BI)                                                              \
  {                                                                              \
    uint32_t d[4];                                                               \
    _Pragma("unroll") for (int k = 0; k < 4; ++k) {                              \
      int4 w = br[k];                                                            \
      uint32_t lo = __builtin_amdgcn_perm((uint32_t)w.y, (uint32_t)w.x, 0x0C0C0400u); \
      uint32_t hi = __builtin_amdgcn_perm((uint32_t)w.w, (uint32_t)w.z, 0x04000C0Cu); \
      d[k] = lo | hi;                                                            \
    }                                                                            \
    const int ch = bq ^ (brow & 15);                                             \
    *(uint4*)&Bs[BI][brow * 256 + ch * 16] = make_uint4(d[0], d[1], d[2], d[3]); \
  }

  // COMPUTE span on Bs[BI] using AU; weave A prefetch of knext into AP
#define COMPUTE_PF(BI, AU, AP, knext, dopf)                                      \
  {                                                                              \
    const int kb16n = (knext) >> 4;                                              \
    _Pragma("unroll") for (int kk = 0; kk < 4; ++kk) {                           \
      i32x4 b[4];                                                                \
      _Pragma("unroll") for (int ni = 0; ni < 4; ++ni) {                         \
        const int row = ni * 16 + (lane & 15);                                   \
        const int ch = (kk * 4 + kc) ^ (row & 15);                               \
        b[ni] = *(const i32x4*)&Bs[BI][row * 256 + ch * 16];                     \
      }                                                                          \
      if (dopf) {                                                                \
        _Pragma("unroll") for (int mi = 0; mi < 2; ++mi) {                       \
          AP[kk * 2 + mi] =                                                      \
              *(const i32x4*)&x8f[(size_t)((kb16n + kk * 4 + kc) * 32 + gmbase + mi) * 256 + \
                                  (lane & 15) * 16];                             \
        }                                                                        \
      }                                                                          \
      __builtin_amdgcn_s_setprio(1);                                             \
      _Pragma("unroll") for (int mi = 0; mi < 2; ++mi)                           \
        _Pragma("unroll") for (int ni = 0; ni < 4; ++ni)                         \
          acc[mi][ni] = __builtin_amdgcn_mfma_i32_16x16x64_i8(AU[kk * 2 + mi], b[ni], \
                                                              acc[mi][ni], 0, 0, 0); \
      __builtin_amdgcn_s_setprio(0);                                             \
    }                                                                            \
  }

  // ---- prologue: span 0 staged into Bs[0]; span 1 B loads in flight ----
  B_ISSUE(0);
  A_ISSUE_ALL(0, aC);
  B_WRITE(0);      // counted vmcnt wait on br(span0) only
  B_ISSUE(BKS);    // span 1 -> written at top of pair iter 0
  LGKM_BAR();      // publish Bs[0]

#pragma unroll 1
  for (int tt = 0; tt < NSPAN; tt += 2) {
    // ---- even span tt: compute Bs[0] with aC; prefetch A(tt+1) -> aN ----
    if (tt + 1 < NSPAN) B_WRITE(1);              // span tt+1 (full-span cover)
    if (tt + 2 < NSPAN) B_ISSUE((tt + 2) * BKS); // refill br
    COMPUTE_PF(0, aC, aN, (tt + 1) * BKS, (tt + 1 < NSPAN));
    if (tt + 1 < NSPAN) LGKM_BAR();              // publish Bs[1]

    // ---- odd span tt+1: compute Bs[1] with aN; prefetch A(tt+2) -> aC ----
    if (tt + 1 < NSPAN) {
      if (tt + 2 < NSPAN) B_WRITE(0);              // span tt+2
      if (tt + 3 < NSPAN) B_ISSUE((tt + 3) * BKS); // refill br
      COMPUTE_PF(1, aN, aC, (tt + 2) * BKS, (tt + 2 < NSPAN));
      if (tt + 2 < NSPAN) LGKM_BAR();              // publish Bs[0]
    }
  }

  // ---- epilogue: out = acc * sx[row] * sw[col] + bias[col] (final) ----
  float sxr[2][4];
#pragma unroll
  for (int mi = 0; mi < 2; ++mi)
#pragma unroll
    for (int r = 0; r < 4; ++r)
      sxr[mi][r] = sx[wm * 32 + mi * 16 + (lane >> 4) * 4 + r];

#pragma unroll
  for (int ni = 0; ni < 4; ++ni) {
    const int col = bn0 + ni * 16 + (lane & 15);
    const float sw = scale[col];
    const float bi = bias[col];
#pragma unroll
    for (int mi = 0; mi < 2; ++mi) {
      const int rowb = wm * 32 + mi * 16 + (lane >> 4) * 4;
#pragma unroll
      for (int r = 0; r < 4; ++r) {
        out[(size_t)(rowb + r) * N_OUT + col] = (float)acc[mi][ni][r] * sxr[mi][r] * sw + bi;
      }
    }
  }
#undef LGKM_BAR
#undef A_ISSUE_ALL
#undef B_ISSUE
#undef B_WRITE
#undef COMPUTE_PF
}

// ---- naive fallback (ws too small; not expected to run) ---------------------
__global__ void qgemm_naive(const float* __restrict__ x, const int* __restrict__ qw,
                            const float* __restrict__ scale, const float* __restrict__ bias,
                            float* __restrict__ out) {
  int o = blockIdx.x * blockDim.x + threadIdx.x;
  if (o >= M_TOK * N_OUT) return;
  int row = o / N_OUT, col = o % N_OUT;
  const float* xr = x + (size_t)row * K_IN;
  const int* wr = qw + (size_t)col * K_IN;
  float acc = 0.f;
  for (int k = 0; k < K_IN; ++k) acc += xr[k] * (float)wr[k];
  out[o] = acc * scale[col] + bias[col];
}

// ---- launch ------------------------------------------------------------------
extern "C" void kernel_launch(void* const* d_in, const int* in_sizes, int n_in,
                              void* d_out, int out_size, void* d_ws, size_t ws_size,
                              hipStream_t stream) {
  const float* x = (const float*)d_in[0];
  const int* qw = (const int*)d_in[1];
  const float* scale = (const float*)d_in[2];
  const float* bias = (const float*)d_in[3];
  float* out = (float*)d_out;

  const size_t sx_bytes = 4096;                  // 512 floats, padded
  const size_t x8_bytes = (size_t)M_TOK * K_IN;  // 2 MB

  if (ws_size >= sx_bytes + x8_bytes) {
    float* sx = (float*)d_ws;
    int8_t* x8f = (int8_t*)((char*)d_ws + sx_bytes);
    xquant_kernel<<<dim3(M_TOK / 4), dim3(256), 0, stream>>>(x, x8f, sx);
    qgemm_i8<<<dim3(N_OUT / BN), dim3(1024), 0, stream>>>(x8f, sx, qw, scale, bias, out);
  } else {
    qgemm_naive<<<dim3((M_TOK * N_OUT + 255) / 256), dim3(256), 0, stream>>>(
        x, qw, scale, bias, out);
  }
}

// Round 23
// 59.955 us; speedup vs baseline: 2.0696x; 2.0696x over previous
//
#include <hip/hip_runtime.h>
#include <stdint.h>

#define M_TOK 512
#define N_OUT 11008
#define K_IN  4096
#define BM 512
#define BN 64
#define BKS 256                 // k per barrier span (4 MFMA k-tiles)
#define NSPAN (K_IN / BKS)      // 16

typedef int i32x4 __attribute__((ext_vector_type(4)));

// =============================================================================
// Pre-pass: per-token-row int8 quantization of x (absmax/127), emitted in
// MFMA-FRAGMENT layout: chunk (kc16 = k>>4, gm = m>>4) stored at
//   x8f[((kc16*32) + gm)*256 + (m&15)*16 + (k&15)]
// A-frag load = fully coalesced dwordx4 from the L2-resident 2MB buffer.
// Verified rounds 11-22 (absmax 4.125).
// =============================================================================
__global__ void xquant_kernel(const float* __restrict__ x, int8_t* __restrict__ x8f,
                              float* __restrict__ sx) {
  const int row = blockIdx.x * 4 + (threadIdx.x >> 6);
  const int lane = threadIdx.x & 63;
  const float4* xr = (const float4*)(x + (size_t)row * K_IN);

  float4 v[16];
  float m = 0.f;
#pragma unroll
  for (int j = 0; j < 16; ++j) {
    v[j] = xr[lane * 16 + j];
    m = fmaxf(m, fmaxf(fmaxf(fabsf(v[j].x), fabsf(v[j].y)),
                       fmaxf(fabsf(v[j].z), fabsf(v[j].w))));
  }
#pragma unroll
  for (int o = 32; o; o >>= 1) m = fmaxf(m, __shfl_xor(m, o));

  const float inv = 127.0f / m;
  if (lane == 0) sx[row] = m / 127.0f;

  uint32_t d[16];
#pragma unroll
  for (int j = 0; j < 16; ++j) {
    int a = __float2int_rn(v[j].x * inv);
    int b = __float2int_rn(v[j].y * inv);
    int c = __float2int_rn(v[j].z * inv);
    int e = __float2int_rn(v[j].w * inv);
    d[j] = (a & 0xFF) | ((b & 0xFF) << 8) | ((c & 0xFF) << 16) | (e << 24);
  }
  const int gm = row >> 4, mr = row & 15;
#pragma unroll
  for (int q = 0; q < 4; ++q) {
    const int kc16 = lane * 4 + q;
    *(uint4*)&x8f[(size_t)(kc16 * 32 + gm) * 256 + mr * 16] =
        make_uint4(d[4 * q], d[4 * q + 1], d[4 * q + 2], d[4 * q + 3]);
  }
}

// =============================================================================
// int8 GEMM, BM=512 (all of M) x BN=64, NO K-split, grid 172 x 1024 thr.
// W HBM-read exactly once; 1 block/CU single round; final outputs direct.
// SPAN = 256 k (4 MFMA k-tiles) per barrier -> 16 barriers/block.
// Per span/wave: 32 MFMA.
//   - B: thread loads 64B contiguous of one W row (fully packed lines)
//     -> pack 16 int8 -> ONE ds_write_b128 per span.
//     Write-at-top: br loaded a full span (~4000cyc) before its ds_write.
//   - A: all 8 frags of span t+1 issued after COMPUTE(t) (L2-hot x8f).
//   - LDS [64 rows][256 int8], chunk ch = c ^ (row&15): frag reads 2-way
//     bank alias = free; ds_write conflict-free.
//   - lgkm-only raw barriers; global loads fly across (counted waits at use).
// MEASURED BEST (round 20): 60.91 us total. Restored verbatim after r21
// (half-span weave, -3.2us) and r22 (register-woven A prefetch, spill,
// -63us) both regressed — the 16-wave lockstep phase-sum is structural.
// =============================================================================
__global__ __launch_bounds__(1024, 4)
void qgemm_i8(const int8_t* __restrict__ x8f, const float* __restrict__ sx,
              const int* __restrict__ qw, const float* __restrict__ scale,
              const float* __restrict__ bias, float* __restrict__ out) {
  __shared__ __align__(16) int8_t Bs[2][BN * BKS];  // 16KB each (32KB total)

  const int tid = threadIdx.x;
  const int lane = tid & 63;
  const int wm = tid >> 6;  // 0..15: wave owns rows wm*32 .. wm*32+31
  const int kc = lane >> 4;

  const int bn0 = blockIdx.x * BN;
  const int gmbase = wm * 2;  // gm = m>>4

  i32x4 acc[2][4] = {};
  i32x4 aS[8];   // span's 8 A-frags (4 kk x 2 mi), statically indexed
  int4 br[4];    // 64B of one W row; write-at-top -> full-span load cover

  const int brow = tid >> 4;  // 0..63: W row within the BN tile
  const int bq = tid & 15;    // 64B unit within the 1024B int32 row span

#define LGKM_BAR() asm volatile("s_waitcnt lgkmcnt(0)\ns_barrier" ::: "memory")

  // all 8 A-frags for span starting at k0 (L2-hot; counted waits at use)
#define A_ISSUE_ALL(k0)                                                          \
  {                                                                              \
    const int kbase16 = (k0) >> 4;                                               \
    _Pragma("unroll") for (int kk = 0; kk < 4; ++kk) {                           \
      _Pragma("unroll") for (int mi = 0; mi < 2; ++mi) {                         \
        aS[kk * 2 + mi] =                                                        \
            *(const i32x4*)&x8f[(size_t)((kbase16 + kk * 4 + kc) * 32 + gmbase + mi) * 256 + \
                                (lane & 15) * 16];                               \
      }                                                                          \
    }                                                                            \
  }

#define B_ISSUE(k0)                                                              \
  {                                                                              \
    const int4* bp = (const int4*)(qw + (size_t)(bn0 + brow) * K_IN + (k0) + bq * 16); \
    _Pragma("unroll") for (int k = 0; k < 4; ++k) br[k] = bp[k];                 \
  }

#define B_WRITE(BI)                                                              \
  {                                                                              \
    uint32_t d[4];                                                               \
    _Pragma("unroll") for (int k = 0; k < 4; ++k) {                              \
      int4 w = br[k];                                                            \
      uint32_t lo = __builtin_amdgcn_perm((uint32_t)w.y, (uint32_t)w.x, 0x0C0C0400u); \
      uint32_t hi = __builtin_amdgcn_perm((uint32_t)w.w, (uint32_t)w.z, 0x04000C0Cu); \
      d[k] = lo | hi;                                                            \
    }                                                                            \
    const int ch = bq ^ (brow & 15);                                             \
    *(uint4*)&Bs[BI][brow * 256 + ch * 16] = make_uint4(d[0], d[1], d[2], d[3]); \
  }

  // 4 k-tiles x (2mi x 4ni) MFMA on Bs[BI] using aS
#define COMPUTE(BI)                                                              \
  {                                                                              \
    _Pragma("unroll") for (int kk = 0; kk < 4; ++kk) {                           \
      i32x4 b[4];                                                                \
      _Pragma("unroll") for (int ni = 0; ni < 4; ++ni) {                         \
        const int row = ni * 16 + (lane & 15);                                   \
        const int ch = (kk * 4 + kc) ^ (row & 15);                               \
        b[ni] = *(const i32x4*)&Bs[BI][row * 256 + ch * 16];                     \
      }                                                                          \
      __builtin_amdgcn_s_setprio(1);                                             \
      _Pragma("unroll") for (int mi = 0; mi < 2; ++mi)                           \
        _Pragma("unroll") for (int ni = 0; ni < 4; ++ni)                         \
          acc[mi][ni] = __builtin_amdgcn_mfma_i32_16x16x64_i8(aS[kk * 2 + mi], b[ni], \
                                                              acc[mi][ni], 0, 0, 0); \
      __builtin_amdgcn_s_setprio(0);                                             \
    }                                                                            \
  }

  // ---- prologue: span 0 staged into Bs[0]; span 1 loads in flight ----
  B_ISSUE(0);
  A_ISSUE_ALL(0);
  B_WRITE(0);      // counted vmcnt wait on br(span0) only
  B_ISSUE(BKS);    // span 1 -> written at top of iter 0, consumed iter 1
  LGKM_BAR();      // publish Bs[0]

#pragma unroll 1
  for (int t = 0; t < NSPAN; ++t) {
    const int cur = t & 1;
    // write span t+1 (br loaded a full span ago -> HBM latency covered);
    // WAR-safe: Bs[cur^1]'s last reader (COMPUTE t-1) is behind the t-1 bar.
    if (t + 1 < NSPAN) B_WRITE(cur ^ 1);
    // refill br with span t+2 (consumed at the top of iter t+1)
    if (t + 2 < NSPAN) B_ISSUE((t + 2) * BKS);

    COMPUTE(cur);  // 32 MFMA/wave on Bs[cur]

    if (t + 1 < NSPAN) {
      A_ISSUE_ALL((t + 1) * BKS);  // L2-hot; lands under bar + next-top staging
      LGKM_BAR();                  // publish Bs[cur^1]
    }
  }

  // ---- epilogue: out = acc * sx[row] * sw[col] + bias[col] (final) ----
  float sxr[2][4];
#pragma unroll
  for (int mi = 0; mi < 2; ++mi)
#pragma unroll
    for (int r = 0; r < 4; ++r)
      sxr[mi][r] = sx[wm * 32 + mi * 16 + (lane >> 4) * 4 + r];

#pragma unroll
  for (int ni = 0; ni < 4; ++ni) {
    const int col = bn0 + ni * 16 + (lane & 15);
    const float sw = scale[col];
    const float bi = bias[col];
#pragma unroll
    for (int mi = 0; mi < 2; ++mi) {
      const int rowb = wm * 32 + mi * 16 + (lane >> 4) * 4;
#pragma unroll
      for (int r = 0; r < 4; ++r) {
        out[(size_t)(rowb + r) * N_OUT + col] = (float)acc[mi][ni][r] * sxr[mi][r] * sw + bi;
      }
    }
  }
#undef LGKM_BAR
#undef A_ISSUE_ALL
#undef B_ISSUE
#undef B_WRITE
#undef COMPUTE
}

// ---- naive fallback (ws too small; not expected to run) ---------------------
__global__ void qgemm_naive(const float* __restrict__ x, const int* __restrict__ qw,
                            const float* __restrict__ scale, const float* __restrict__ bias,
                            float* __restrict__ out) {
  int o = blockIdx.x * blockDim.x + threadIdx.x;
  if (o >= M_TOK * N_OUT) return;
  int row = o / N_OUT, col = o % N_OUT;
  const float* xr = x + (size_t)row * K_IN;
  const int* wr = qw + (size_t)col * K_IN;
  float acc = 0.f;
  for (int k = 0; k < K_IN; ++k) acc += xr[k] * (float)wr[k];
  out[o] = acc * scale[col] + bias[col];
}

// ---- launch ------------------------------------------------------------------
extern "C" void kernel_launch(void* const* d_in, const int* in_sizes, int n_in,
                              void* d_out, int out_size, void* d_ws, size_t ws_size,
                              hipStream_t stream) {
  const float* x = (const float*)d_in[0];
  const int* qw = (const int*)d_in[1];
  const float* scale = (const float*)d_in[2];
  const float* bias = (const float*)d_in[3];
  float* out = (float*)d_out;

  const size_t sx_bytes = 4096;                  // 512 floats, padded
  const size_t x8_bytes = (size_t)M_TOK * K_IN;  // 2 MB

  if (ws_size >= sx_bytes + x8_bytes) {
    float* sx = (float*)d_ws;
    int8_t* x8f = (int8_t*)((char*)d_ws + sx_bytes);
    xquant_kernel<<<dim3(M_TOK / 4), dim3(256), 0, stream>>>(x, x8f, sx);
    qgemm_i8<<<dim3(N_OUT / BN), dim3(1024), 0, stream>>>(x8f, sx, qw, scale, bias, out);
  } else {
    qgemm_naive<<<dim3((M_TOK * N_OUT + 255) / 256), dim3(256), 0, stream>>>(
        x, qw, scale, bias, out);
  }
}